// Round 10
// baseline (178.137 us; speedup 1.0000x reference)
//
#include <hip/hip_runtime.h>
#include <math.h>

#define LVL 16
#define TBL 65536
#define BATCH 8
#define NPIX 65536       // 256*256
#define SDIM 512
#define HPRIME 2654435761u

typedef __attribute__((ext_vector_type(2))) float f32x2;

struct ResPack { int r[LVL]; };
struct LvlOff { int o[LVL]; };   // per-level offset into LDS row-cache (float2 units)

// ws layout (floats): [0, 17152) weff (8 x 2144), [17152, 17920) style (8 x 96)
#define WEFF_STRIDE 2144
#define STYLE_OFF   17152

// ---------------------------------------------------------------------------
// Kernel A1: style dots, one wave per (b, v). 768 waves.
// ---------------------------------------------------------------------------
__global__ __launch_bounds__(256) void style_kernel(
    const float* __restrict__ s,
    const float* __restrict__ aw0, const float* __restrict__ ab0,
    const float* __restrict__ aw1, const float* __restrict__ ab1,
    const float* __restrict__ aw2, const float* __restrict__ ab2,
    float* __restrict__ ws)
{
    const int wave_id = blockIdx.x * 4 + ((int)threadIdx.x >> 6);   // [0, 768)
    const int lane    = (int)threadIdx.x & 63;
    const int b = wave_id / 96;
    const int v = wave_id % 96;

    const float* row; float bias;
    if (v < 32)      { row = aw0 + v * SDIM;        bias = ab0[v]; }
    else if (v < 64) { row = aw1 + (v - 32) * SDIM; bias = ab1[v - 32]; }
    else             { row = aw2 + (v - 64) * SDIM; bias = ab2[v - 64]; }

    const float* sb = s + b * SDIM;
    float acc = 0.f;
    #pragma unroll
    for (int j = 0; j < SDIM / 64; ++j) {
        const int k = lane + j * 64;
        acc += sb[k] * row[k];
    }
    #pragma unroll
    for (int off = 32; off >= 1; off >>= 1) acc += __shfl_xor(acc, off, 64);
    if (lane == 0) ws[STYLE_OFF + b * 96 + v] = acc + bias;
}

// ---------------------------------------------------------------------------
// Kernel A2: demod + modulated weights, paired layout (round-7 verified).
// weff per b: [0,1024) W0p {o2,o2+16} interleaved, [1024,2048) W1p,
// [2048,2144) W2 [3][32].
// ---------------------------------------------------------------------------
__global__ __launch_bounds__(256) void weff_kernel(
    const float* __restrict__ w0, const float* __restrict__ w1, const float* __restrict__ w2,
    float* __restrict__ ws)
{
    const int b = blockIdx.x;
    __shared__ float st[96];
    __shared__ float demod[67];
    const int tid = (int)threadIdx.x;

    if (tid < 96) st[tid] = ws[STYLE_OFF + b * 96 + tid];
    __syncthreads();

    if (tid < 67) {
        const int o = tid;
        const float* wrow; const float* stp;
        if (o < 32)      { wrow = w0 + o * 32;        stp = st; }
        else if (o < 64) { wrow = w1 + (o - 32) * 32; stp = st + 32; }
        else             { wrow = w2 + (o - 64) * 32; stp = st + 64; }
        float sum = 0.f;
        #pragma unroll
        for (int i = 0; i < 32; ++i) { float v = wrow[i] * stp[i]; sum += v * v; }
        demod[o] = 1.0f / sqrtf(sum + 1e-8f);
    }
    __syncthreads();

    float* outp = ws + b * WEFF_STRIDE;
    for (int idx = tid; idx < 2144; idx += 256) {
        float v;
        if (idx < 1024) {
            const int o2 = idx >> 6, rem = idx & 63, i = rem >> 1, h = rem & 1;
            const int o = o2 + 16 * h;
            v = w0[o * 32 + i] * st[i] * demod[o];
        } else if (idx < 2048) {
            const int j = idx - 1024;
            const int o2 = j >> 6, rem = j & 63, i = rem >> 1, h = rem & 1;
            const int o = o2 + 16 * h;
            v = w1[o * 32 + i] * st[32 + i] * demod[32 + o];
        } else {
            const int j = idx - 2048; const int o = j >> 5, i = j & 31;
            v = w2[j] * st[64 + i] * demod[64 + o];
        }
        outp[idx] = v;
    }
}

// ---------------------------------------------------------------------------
// Kernel B: XCD-swizzled, 1 px/thread, per-block LDS row-cache.
// A block is one image row (cy uniform), so each level needs only grid rows
// y0, y0+1: stage sum_l 2*R_l = 2876 float2 (23 KB) from the hash tables into
// LDS (each (level,row) is a permuted 2KB window -> line-coalesced), then all
// bilinear reads are LDS hits. Hash/interp/MLP math byte-identical to the
// verified round-9 path.
// ---------------------------------------------------------------------------
__global__ __launch_bounds__(256) void fused_kernel(
    const float* __restrict__ tables,   // [B, L, T, 2]
    const float* __restrict__ coords,   // [N, 2]
    const float* __restrict__ weff,     // ws: paired weights per batch
    const float* __restrict__ b0, const float* __restrict__ b1, const float* __restrict__ b2,
    float* __restrict__ out,            // [B, 3, 256, 256]
    ResPack res, LvlOff loff)
{
    __shared__ float2 rowc[3072];       // 24576 B; 2876 used

    const int tid   = (int)threadIdx.x;
    const int b     = blockIdx.x & 7;           // XCD-affinity: batch <-> XCD
    const int chunk = blockIdx.x >> 3;          // = image row y
    const int n     = chunk * 256 + tid;

    const float cx = coords[2 * n];
    const float cy = coords[2 * n + 1];         // uniform within the block
    const float* tb = tables + (size_t)b * (LVL * TBL * 2);

    // ---- stage rows y0(l), y0(l)+1 of every level into LDS -----------------
    #pragma unroll
    for (int l = 0; l < LVL; ++l) {
        const int R = res.r[l];
        const float py = cy * (float)(R - 1);
        const int y0 = (int)floorf(py);         // uniform across block
        const float2* tl = (const float2*)(tb + l * (TBL * 2));
        for (int i = tid; i < 2 * R; i += 256) {
            const int rsel = (i >= R) ? 1 : 0;
            const int x = i - rsel * R;
            const unsigned yy = (unsigned)(y0 + rsel);
            const unsigned h = ((unsigned)x ^ (yy * HPRIME)) & 0xFFFFu;
            rowc[loff.o[l] + i] = tl[h];
        }
    }
    __syncthreads();

    // ---- bilinear from LDS -------------------------------------------------
    f32x2 feat2[16];
    #pragma unroll
    for (int l = 0; l < LVL; ++l) {
        const int R = res.r[l];
        const float rm1 = (float)(R - 1);
        const float px = cx * rm1, py = cy * rm1;
        const float fpx = floorf(px), fpy = floorf(py);
        const float fx = px - fpx, fy = py - fpy;
        const int x0 = (int)fpx;
        const int base = loff.o[l] + x0;        // row0 at base, row1 at base+R
        const float2 g00 = rowc[base];
        const float2 g10 = rowc[base + 1];
        const float2 g01 = rowc[base + R];
        const float2 g11 = rowc[base + R + 1];
        const float w00 = (1.f - fx) * (1.f - fy);
        const float w10 = fx * (1.f - fy);
        const float w01 = (1.f - fx) * fy;
        const float w11 = fx * fy;
        f32x2 acc;
        acc[0] = g00.x * w00; acc[1] = g00.y * w00;
        acc[0] += g10.x * w10; acc[1] += g10.y * w10;
        acc[0] += g01.x * w01; acc[1] += g01.y * w01;
        acc[0] += g11.x * w11; acc[1] += g11.y * w11;
        feat2[l] = acc;
    }

    const f32x2* W0p = (const f32x2*)(weff + (size_t)b * WEFF_STRIDE);         // [16][32]
    const f32x2* W1p = W0p + 512;                                              // [16][32]
    const float* W2  = weff + (size_t)b * WEFF_STRIDE + 2048;                  // [3][32]
    const float* featf = (const float*)feat2;                                  // feat[32]

    f32x2 h1p[16];
    #pragma unroll
    for (int o2 = 0; o2 < 16; ++o2) {
        f32x2 acc; acc[0] = b0[o2]; acc[1] = b0[o2 + 16];
        #pragma unroll
        for (int i = 0; i < 32; ++i) {
            f32x2 fb; fb[0] = featf[i]; fb[1] = featf[i];
            acc += W0p[o2 * 32 + i] * fb;
        }
        acc[0] = fmaxf(acc[0], 0.f); acc[1] = fmaxf(acc[1], 0.f);
        h1p[o2] = acc;
    }

    f32x2 h2p[16];
    #pragma unroll
    for (int o2 = 0; o2 < 16; ++o2) {
        f32x2 acc; acc[0] = b1[o2]; acc[1] = b1[o2 + 16];
        #pragma unroll
        for (int i = 0; i < 32; ++i) {
            const float hv = h1p[i & 15][i >> 4];
            f32x2 fb; fb[0] = hv; fb[1] = hv;
            acc += W1p[o2 * 32 + i] * fb;
        }
        acc[0] = fmaxf(acc[0], 0.f); acc[1] = fmaxf(acc[1], 0.f);
        h2p[o2] = acc;
    }

    #pragma unroll
    for (int o = 0; o < 3; ++o) {
        float acc = b2[o];
        #pragma unroll
        for (int i = 0; i < 32; ++i)
            acc = fmaf(W2[o * 32 + i], h2p[i & 15][i >> 4], acc);
        out[((size_t)(b * 3 + o) << 16) + n] = tanhf(acc);
    }
}

// ---------------------------------------------------------------------------
extern "C" void kernel_launch(void* const* d_in, const int* in_sizes, int n_in,
                              void* d_out, int out_size, void* d_ws, size_t ws_size,
                              hipStream_t stream) {
    const float* x      = (const float*)d_in[0];
    const float* s      = (const float*)d_in[1];
    const float* coords = (const float*)d_in[2];
    const float* w0  = (const float*)d_in[3];
    const float* aw0 = (const float*)d_in[4];
    const float* ab0 = (const float*)d_in[5];
    const float* b0  = (const float*)d_in[6];
    const float* w1  = (const float*)d_in[7];
    const float* aw1 = (const float*)d_in[8];
    const float* ab1 = (const float*)d_in[9];
    const float* b1  = (const float*)d_in[10];
    const float* w2  = (const float*)d_in[11];
    const float* aw2 = (const float*)d_in[12];
    const float* ab2 = (const float*)d_in[13];
    const float* b2  = (const float*)d_in[14];
    float* out = (float*)d_out;
    float* ws  = (float*)d_ws;    // 17920 floats = 71680 B

    ResPack rp; LvlOff lo;
    int acc = 0;
    const double g = pow(256.0 / 16.0, 1.0 / 15.0);
    for (int l = 0; l < LVL; ++l) {
        double r = 16.0 * pow(g, (double)l);
        long ri = lround(r);
        if (ri > 256) ri = 256;
        rp.r[l] = (int)ri;
        lo.o[l] = acc;
        acc += 2 * (int)ri;        // two staged rows per level; total 2876 <= 3072
    }

    hipLaunchKernelGGL(style_kernel, dim3(192), dim3(256), 0, stream,
                       s, aw0, ab0, aw1, ab1, aw2, ab2, ws);
    hipLaunchKernelGGL(weff_kernel, dim3(BATCH), dim3(256), 0, stream,
                       w0, w1, w2, ws);
    hipLaunchKernelGGL(fused_kernel, dim3(NPIX / 256 * BATCH), dim3(256), 0, stream,
                       x, coords, ws, b0, b1, b2, out, rp, lo);
}

// Round 11
// 176.971 us; speedup vs baseline: 1.0066x; 1.0066x over previous
//
#include <hip/hip_runtime.h>
#include <math.h>

#define LVL 16
#define TBL 65536
#define BATCH 8
#define NPIX 65536       // 256*256
#define SDIM 512
#define HPRIME 2654435761u

typedef __attribute__((ext_vector_type(2))) float f32x2;

struct ResPack { int r[LVL]; };
struct LvlOff { int o[LVL]; };   // per-level offset into LDS row-cache (float2 units), stride 5*R

// ws layout (floats): [0, 17152) weff (8 x 2144), [17152, 17920) style (8 x 96)
#define WEFF_STRIDE 2144
#define STYLE_OFF   17152

// ---------------------------------------------------------------------------
// Kernel A1: style dots, one wave per (b, v). 768 waves.
// ---------------------------------------------------------------------------
__global__ __launch_bounds__(256) void style_kernel(
    const float* __restrict__ s,
    const float* __restrict__ aw0, const float* __restrict__ ab0,
    const float* __restrict__ aw1, const float* __restrict__ ab1,
    const float* __restrict__ aw2, const float* __restrict__ ab2,
    float* __restrict__ ws)
{
    const int wave_id = blockIdx.x * 4 + ((int)threadIdx.x >> 6);   // [0, 768)
    const int lane    = (int)threadIdx.x & 63;
    const int b = wave_id / 96;
    const int v = wave_id % 96;

    const float* row; float bias;
    if (v < 32)      { row = aw0 + v * SDIM;        bias = ab0[v]; }
    else if (v < 64) { row = aw1 + (v - 32) * SDIM; bias = ab1[v - 32]; }
    else             { row = aw2 + (v - 64) * SDIM; bias = ab2[v - 64]; }

    const float* sb = s + b * SDIM;
    float acc = 0.f;
    #pragma unroll
    for (int j = 0; j < SDIM / 64; ++j) {
        const int k = lane + j * 64;
        acc += sb[k] * row[k];
    }
    #pragma unroll
    for (int off = 32; off >= 1; off >>= 1) acc += __shfl_xor(acc, off, 64);
    if (lane == 0) ws[STYLE_OFF + b * 96 + v] = acc + bias;
}

// ---------------------------------------------------------------------------
// Kernel A2: demod + modulated weights, paired layout (round-7 verified).
// weff per b: [0,1024) W0p {o2,o2+16} interleaved, [1024,2048) W1p,
// [2048,2144) W2 [3][32].
// ---------------------------------------------------------------------------
__global__ __launch_bounds__(256) void weff_kernel(
    const float* __restrict__ w0, const float* __restrict__ w1, const float* __restrict__ w2,
    float* __restrict__ ws)
{
    const int b = blockIdx.x;
    __shared__ float st[96];
    __shared__ float demod[67];
    const int tid = (int)threadIdx.x;

    if (tid < 96) st[tid] = ws[STYLE_OFF + b * 96 + tid];
    __syncthreads();

    if (tid < 67) {
        const int o = tid;
        const float* wrow; const float* stp;
        if (o < 32)      { wrow = w0 + o * 32;        stp = st; }
        else if (o < 64) { wrow = w1 + (o - 32) * 32; stp = st + 32; }
        else             { wrow = w2 + (o - 64) * 32; stp = st + 64; }
        float sum = 0.f;
        #pragma unroll
        for (int i = 0; i < 32; ++i) { float v = wrow[i] * stp[i]; sum += v * v; }
        demod[o] = 1.0f / sqrtf(sum + 1e-8f);
    }
    __syncthreads();

    float* outp = ws + b * WEFF_STRIDE;
    for (int idx = tid; idx < 2144; idx += 256) {
        float v;
        if (idx < 1024) {
            const int o2 = idx >> 6, rem = idx & 63, i = rem >> 1, h = rem & 1;
            const int o = o2 + 16 * h;
            v = w0[o * 32 + i] * st[i] * demod[o];
        } else if (idx < 2048) {
            const int j = idx - 1024;
            const int o2 = j >> 6, rem = j & 63, i = rem >> 1, h = rem & 1;
            const int o = o2 + 16 * h;
            v = w1[o * 32 + i] * st[32 + i] * demod[32 + o];
        } else {
            const int j = idx - 2048; const int o = j >> 5, i = j & 31;
            v = w2[j] * st[64 + i] * demod[64 + o];
        }
        outp[idx] = v;
    }
}

// ---------------------------------------------------------------------------
// Kernel B: mega-block LDS row-cache. Block = 1024 threads = 4 image rows.
// Per level stage grid rows y0min..y0min+4 (5 rows, 57.9 KB total) once per
// 1024 pixels (4x better staging amortization than round 10), then all
// bilinear reads are LDS hits. Interp + paired packed-fp32 MLP bitwise
// identical to the verified round-9 path. bid&7 keeps batch<->XCD affinity.
// ---------------------------------------------------------------------------
__global__ __launch_bounds__(1024) void fused_kernel(
    const float* __restrict__ tables,   // [B, L, T, 2]
    const float* __restrict__ coords,   // [N, 2]
    const float* __restrict__ weff,     // ws: paired weights per batch
    const float* __restrict__ b0, const float* __restrict__ b1, const float* __restrict__ b2,
    float* __restrict__ out,            // [B, 3, 256, 256]
    ResPack res, LvlOff loff)
{
    __shared__ float2 rowc[7232];       // 57856 B; 7190 used

    const int tid   = (int)threadIdx.x;
    const int b     = blockIdx.x & 7;           // XCD-affinity: batch <-> XCD
    const int chunk = blockIdx.x >> 3;          // [0,64): group of 4 image rows
    const int n     = (chunk << 10) + tid;

    const float cx = coords[2 * n];
    const float cy = coords[2 * n + 1];
    const float cyTop = coords[(chunk << 11) + 1];   // cy of the block's first row
    const float* tb = tables + (size_t)b * (LVL * TBL * 2);

    // ---- stage rows y0min..y0min+4 of every level into LDS -----------------
    #pragma unroll
    for (int l = 0; l < LVL; ++l) {
        const int R = res.r[l];
        const int y0min = (int)floorf(cyTop * (float)(R - 1));   // block-uniform
        const float2* tl = (const float2*)(tb + l * (TBL * 2));
        for (int i = tid; i < 5 * R; i += 1024) {
            int x = i, rsel = 0;
            #pragma unroll
            for (int t = 0; t < 4; ++t) { if (x >= R) { x -= R; ++rsel; } }
            const unsigned yy = (unsigned)(y0min + rsel);
            const unsigned h = ((unsigned)x ^ (yy * HPRIME)) & 0xFFFFu;
            rowc[loff.o[l] + i] = tl[h];    // rsel*R + x == i
        }
    }
    __syncthreads();

    // ---- bilinear from LDS (bitwise identical to round-9 math) -------------
    f32x2 feat2[16];
    #pragma unroll
    for (int l = 0; l < LVL; ++l) {
        const int R = res.r[l];
        const float rm1 = (float)(R - 1);
        const float px = cx * rm1, py = cy * rm1;
        const float fpx = floorf(px), fpy = floorf(py);
        const float fx = px - fpx, fy = py - fpy;
        const int x0 = (int)fpx;
        const int y0 = (int)fpy;
        const int y0min = (int)floorf(cyTop * rm1);
        const int base = loff.o[l] + (y0 - y0min) * R + x0;   // row+1 at base+R
        const float2 g00 = rowc[base];
        const float2 g10 = rowc[base + 1];
        const float2 g01 = rowc[base + R];
        const float2 g11 = rowc[base + R + 1];
        const float w00 = (1.f - fx) * (1.f - fy);
        const float w10 = fx * (1.f - fy);
        const float w01 = (1.f - fx) * fy;
        const float w11 = fx * fy;
        f32x2 acc;
        acc[0] = g00.x * w00; acc[1] = g00.y * w00;
        acc[0] += g10.x * w10; acc[1] += g10.y * w10;
        acc[0] += g01.x * w01; acc[1] += g01.y * w01;
        acc[0] += g11.x * w11; acc[1] += g11.y * w11;
        feat2[l] = acc;
    }

    const f32x2* W0p = (const f32x2*)(weff + (size_t)b * WEFF_STRIDE);         // [16][32]
    const f32x2* W1p = W0p + 512;                                              // [16][32]
    const float* W2  = weff + (size_t)b * WEFF_STRIDE + 2048;                  // [3][32]
    const float* featf = (const float*)feat2;                                  // feat[32]

    f32x2 h1p[16];
    #pragma unroll
    for (int o2 = 0; o2 < 16; ++o2) {
        f32x2 acc; acc[0] = b0[o2]; acc[1] = b0[o2 + 16];
        #pragma unroll
        for (int i = 0; i < 32; ++i) {
            f32x2 fb; fb[0] = featf[i]; fb[1] = featf[i];
            acc += W0p[o2 * 32 + i] * fb;
        }
        acc[0] = fmaxf(acc[0], 0.f); acc[1] = fmaxf(acc[1], 0.f);
        h1p[o2] = acc;
    }

    f32x2 h2p[16];
    #pragma unroll
    for (int o2 = 0; o2 < 16; ++o2) {
        f32x2 acc; acc[0] = b1[o2]; acc[1] = b1[o2 + 16];
        #pragma unroll
        for (int i = 0; i < 32; ++i) {
            const float hv = h1p[i & 15][i >> 4];
            f32x2 fb; fb[0] = hv; fb[1] = hv;
            acc += W1p[o2 * 32 + i] * fb;
        }
        acc[0] = fmaxf(acc[0], 0.f); acc[1] = fmaxf(acc[1], 0.f);
        h2p[o2] = acc;
    }

    #pragma unroll
    for (int o = 0; o < 3; ++o) {
        float acc = b2[o];
        #pragma unroll
        for (int i = 0; i < 32; ++i)
            acc = fmaf(W2[o * 32 + i], h2p[i & 15][i >> 4], acc);
        out[((size_t)(b * 3 + o) << 16) + n] = tanhf(acc);
    }
}

// ---------------------------------------------------------------------------
extern "C" void kernel_launch(void* const* d_in, const int* in_sizes, int n_in,
                              void* d_out, int out_size, void* d_ws, size_t ws_size,
                              hipStream_t stream) {
    const float* x      = (const float*)d_in[0];
    const float* s      = (const float*)d_in[1];
    const float* coords = (const float*)d_in[2];
    const float* w0  = (const float*)d_in[3];
    const float* aw0 = (const float*)d_in[4];
    const float* ab0 = (const float*)d_in[5];
    const float* b0  = (const float*)d_in[6];
    const float* w1  = (const float*)d_in[7];
    const float* aw1 = (const float*)d_in[8];
    const float* ab1 = (const float*)d_in[9];
    const float* b1  = (const float*)d_in[10];
    const float* w2  = (const float*)d_in[11];
    const float* aw2 = (const float*)d_in[12];
    const float* ab2 = (const float*)d_in[13];
    const float* b2  = (const float*)d_in[14];
    float* out = (float*)d_out;
    float* ws  = (float*)d_ws;    // 17920 floats = 71680 B

    ResPack rp; LvlOff lo;
    int acc = 0;
    const double g = pow(256.0 / 16.0, 1.0 / 15.0);
    for (int l = 0; l < LVL; ++l) {
        double r = 16.0 * pow(g, (double)l);
        long ri = lround(r);
        if (ri > 256) ri = 256;
        rp.r[l] = (int)ri;
        lo.o[l] = acc;
        acc += 5 * (int)ri;        // five staged rows per level; total 7190 <= 7232
    }

    hipLaunchKernelGGL(style_kernel, dim3(192), dim3(256), 0, stream,
                       s, aw0, ab0, aw1, ab1, aw2, ab2, ws);
    hipLaunchKernelGGL(weff_kernel, dim3(BATCH), dim3(256), 0, stream,
                       w0, w1, w2, ws);
    hipLaunchKernelGGL(fused_kernel, dim3(NPIX / 1024 * BATCH), dim3(1024), 0, stream,
                       x, coords, ws, b0, b1, b2, out, rp, lo);
}

// Round 12
// 171.312 us; speedup vs baseline: 1.0398x; 1.0330x over previous
//
#include <hip/hip_runtime.h>
#include <math.h>

#define LVL 16
#define TBL 65536
#define BATCH 8
#define NPIX 65536       // 256*256
#define SDIM 512
#define HPRIME 2654435761u

typedef __attribute__((ext_vector_type(2))) float f32x2;

struct ResPack { int r[LVL]; };
struct LvlOff { int o[LVL]; };   // per-level offset into LDS row-cache (float2 units), stride 3*R

// ws layout (floats): [0, 17152) weff (8 x 2144), [17152, 17920) style (8 x 96)
#define WEFF_STRIDE 2144
#define STYLE_OFF   17152

static __device__ __forceinline__ f32x2 splat2(float v) { f32x2 r = {v, v}; return r; }

// ---------------------------------------------------------------------------
// Kernel A1: style dots, one wave per (b, v). 768 waves.
// ---------------------------------------------------------------------------
__global__ __launch_bounds__(256) void style_kernel(
    const float* __restrict__ s,
    const float* __restrict__ aw0, const float* __restrict__ ab0,
    const float* __restrict__ aw1, const float* __restrict__ ab1,
    const float* __restrict__ aw2, const float* __restrict__ ab2,
    float* __restrict__ ws)
{
    const int wave_id = blockIdx.x * 4 + ((int)threadIdx.x >> 6);   // [0, 768)
    const int lane    = (int)threadIdx.x & 63;
    const int b = wave_id / 96;
    const int v = wave_id % 96;

    const float* row; float bias;
    if (v < 32)      { row = aw0 + v * SDIM;        bias = ab0[v]; }
    else if (v < 64) { row = aw1 + (v - 32) * SDIM; bias = ab1[v - 32]; }
    else             { row = aw2 + (v - 64) * SDIM; bias = ab2[v - 64]; }

    const float* sb = s + b * SDIM;
    float acc = 0.f;
    #pragma unroll
    for (int j = 0; j < SDIM / 64; ++j) {
        const int k = lane + j * 64;
        acc += sb[k] * row[k];
    }
    #pragma unroll
    for (int off = 32; off >= 1; off >>= 1) acc += __shfl_xor(acc, off, 64);
    if (lane == 0) ws[STYLE_OFF + b * 96 + v] = acc + bias;
}

// ---------------------------------------------------------------------------
// Kernel A2: demod + modulated weights, paired layout (round-7 verified).
// weff per b: [0,1024) W0p {o2,o2+16} interleaved, [1024,2048) W1p,
// [2048,2144) W2 [3][32].
// ---------------------------------------------------------------------------
__global__ __launch_bounds__(256) void weff_kernel(
    const float* __restrict__ w0, const float* __restrict__ w1, const float* __restrict__ w2,
    float* __restrict__ ws)
{
    const int b = blockIdx.x;
    __shared__ float st[96];
    __shared__ float demod[67];
    const int tid = (int)threadIdx.x;

    if (tid < 96) st[tid] = ws[STYLE_OFF + b * 96 + tid];
    __syncthreads();

    if (tid < 67) {
        const int o = tid;
        const float* wrow; const float* stp;
        if (o < 32)      { wrow = w0 + o * 32;        stp = st; }
        else if (o < 64) { wrow = w1 + (o - 32) * 32; stp = st + 32; }
        else             { wrow = w2 + (o - 64) * 32; stp = st + 64; }
        float sum = 0.f;
        #pragma unroll
        for (int i = 0; i < 32; ++i) { float v = wrow[i] * stp[i]; sum += v * v; }
        demod[o] = 1.0f / sqrtf(sum + 1e-8f);
    }
    __syncthreads();

    float* outp = ws + b * WEFF_STRIDE;
    for (int idx = tid; idx < 2144; idx += 256) {
        float v;
        if (idx < 1024) {
            const int o2 = idx >> 6, rem = idx & 63, i = rem >> 1, h = rem & 1;
            const int o = o2 + 16 * h;
            v = w0[o * 32 + i] * st[i] * demod[o];
        } else if (idx < 2048) {
            const int j = idx - 1024;
            const int o2 = j >> 6, rem = j & 63, i = rem >> 1, h = rem & 1;
            const int o = o2 + 16 * h;
            v = w1[o * 32 + i] * st[32 + i] * demod[32 + o];
        } else {
            const int j = idx - 2048; const int o = j >> 5, i = j & 31;
            v = w2[j] * st[64 + i] * demod[64 + o];
        }
        outp[idx] = v;
    }
}

// ---------------------------------------------------------------------------
// Kernel B: 512-thread blocks = 2 image rows. Per level stage grid rows
// y0min..y0min+2 (3 rows, 34.5 KB) into LDS once per 512 px, then bilinear
// from LDS. __launch_bounds__(512,4) -> VGPR cap 128 (demand ~80, NO spill;
// round-11's (1024) cap=64 spilled ~7 regs/thread -> 14 MB scratch traffic).
// MLP/interp use __builtin_elementwise_fma on f32x2 -> v_pk_fma_f32.
// Per-channel products and accumulation order unchanged -> same absmax.
// ---------------------------------------------------------------------------
__global__ __launch_bounds__(512, 4) void fused_kernel(
    const float* __restrict__ tables,   // [B, L, T, 2]
    const float* __restrict__ coords,   // [N, 2]
    const float* __restrict__ weff,     // ws: paired weights per batch
    const float* __restrict__ b0, const float* __restrict__ b1, const float* __restrict__ b2,
    float* __restrict__ out,            // [B, 3, 256, 256]
    ResPack res, LvlOff loff)
{
    __shared__ float2 rowc[4352];       // 34816 B; 4314 used

    const int tid   = (int)threadIdx.x;
    const int b     = blockIdx.x & 7;           // XCD-affinity: batch <-> XCD
    const int chunk = blockIdx.x >> 3;          // [0,128): pair of image rows
    const int n     = (chunk << 9) + tid;

    const float cx = coords[2 * n];
    const float cy = coords[2 * n + 1];
    const float cyTop = coords[(chunk << 10) + 1];   // cy of the block's first row
    const float* tb = tables + (size_t)b * (LVL * TBL * 2);

    // ---- stage rows y0min..y0min+2 of every level into LDS -----------------
    #pragma unroll
    for (int l = 0; l < LVL; ++l) {
        const int R = res.r[l];
        const int y0min = (int)floorf(cyTop * (float)(R - 1));   // block-uniform
        const float2* tl = (const float2*)(tb + l * (TBL * 2));
        for (int i = tid; i < 3 * R; i += 512) {
            int x = i, rsel = 0;
            #pragma unroll
            for (int t = 0; t < 2; ++t) { if (x >= R) { x -= R; ++rsel; } }
            const unsigned yy = (unsigned)(y0min + rsel);
            const unsigned h = ((unsigned)x ^ (yy * HPRIME)) & 0xFFFFu;
            rowc[loff.o[l] + i] = tl[h];    // rsel*R + x == i
        }
    }
    __syncthreads();

    // ---- bilinear from LDS (same products/order as verified path) ----------
    f32x2 feat2[16];
    #pragma unroll
    for (int l = 0; l < LVL; ++l) {
        const int R = res.r[l];
        const float rm1 = (float)(R - 1);
        const float px = cx * rm1, py = cy * rm1;
        const float fpx = floorf(px), fpy = floorf(py);
        const float fx = px - fpx, fy = py - fpy;
        const int x0 = (int)fpx;
        const int y0 = (int)fpy;
        const int y0min = (int)floorf(cyTop * rm1);
        const int base = loff.o[l] + (y0 - y0min) * R + x0;   // next row at +R
        const float2 g00 = rowc[base];
        const float2 g10 = rowc[base + 1];
        const float2 g01 = rowc[base + R];
        const float2 g11 = rowc[base + R + 1];
        const float w00 = (1.f - fx) * (1.f - fy);
        const float w10 = fx * (1.f - fy);
        const float w01 = (1.f - fx) * fy;
        const float w11 = fx * fy;
        f32x2 acc, gg;
        gg[0] = g00.x; gg[1] = g00.y; acc = gg * splat2(w00);
        gg[0] = g10.x; gg[1] = g10.y; acc = __builtin_elementwise_fma(gg, splat2(w10), acc);
        gg[0] = g01.x; gg[1] = g01.y; acc = __builtin_elementwise_fma(gg, splat2(w01), acc);
        gg[0] = g11.x; gg[1] = g11.y; acc = __builtin_elementwise_fma(gg, splat2(w11), acc);
        feat2[l] = acc;
    }

    const f32x2* W0p = (const f32x2*)(weff + (size_t)b * WEFF_STRIDE);         // [16][32]
    const f32x2* W1p = W0p + 512;                                              // [16][32]
    const float* W2  = weff + (size_t)b * WEFF_STRIDE + 2048;                  // [3][32]
    const float* featf = (const float*)feat2;                                  // feat[32]

    f32x2 h1p[16];
    #pragma unroll
    for (int o2 = 0; o2 < 16; ++o2) {
        f32x2 acc; acc[0] = b0[o2]; acc[1] = b0[o2 + 16];
        #pragma unroll
        for (int i = 0; i < 32; ++i)
            acc = __builtin_elementwise_fma(W0p[o2 * 32 + i], splat2(featf[i]), acc);
        acc[0] = fmaxf(acc[0], 0.f); acc[1] = fmaxf(acc[1], 0.f);
        h1p[o2] = acc;
    }

    f32x2 h2p[16];
    #pragma unroll
    for (int o2 = 0; o2 < 16; ++o2) {
        f32x2 acc; acc[0] = b1[o2]; acc[1] = b1[o2 + 16];
        #pragma unroll
        for (int i = 0; i < 32; ++i)
            acc = __builtin_elementwise_fma(W1p[o2 * 32 + i], splat2(h1p[i & 15][i >> 4]), acc);
        acc[0] = fmaxf(acc[0], 0.f); acc[1] = fmaxf(acc[1], 0.f);
        h2p[o2] = acc;
    }

    #pragma unroll
    for (int o = 0; o < 3; ++o) {
        float acc = b2[o];
        #pragma unroll
        for (int i = 0; i < 32; ++i)
            acc = fmaf(W2[o * 32 + i], h2p[i & 15][i >> 4], acc);
        out[((size_t)(b * 3 + o) << 16) + n] = tanhf(acc);
    }
}

// ---------------------------------------------------------------------------
extern "C" void kernel_launch(void* const* d_in, const int* in_sizes, int n_in,
                              void* d_out, int out_size, void* d_ws, size_t ws_size,
                              hipStream_t stream) {
    const float* x      = (const float*)d_in[0];
    const float* s      = (const float*)d_in[1];
    const float* coords = (const float*)d_in[2];
    const float* w0  = (const float*)d_in[3];
    const float* aw0 = (const float*)d_in[4];
    const float* ab0 = (const float*)d_in[5];
    const float* b0  = (const float*)d_in[6];
    const float* w1  = (const float*)d_in[7];
    const float* aw1 = (const float*)d_in[8];
    const float* ab1 = (const float*)d_in[9];
    const float* b1  = (const float*)d_in[10];
    const float* w2  = (const float*)d_in[11];
    const float* aw2 = (const float*)d_in[12];
    const float* ab2 = (const float*)d_in[13];
    const float* b2  = (const float*)d_in[14];
    float* out = (float*)d_out;
    float* ws  = (float*)d_ws;    // 17920 floats = 71680 B

    ResPack rp; LvlOff lo;
    int acc = 0;
    const double g = pow(256.0 / 16.0, 1.0 / 15.0);
    for (int l = 0; l < LVL; ++l) {
        double r = 16.0 * pow(g, (double)l);
        long ri = lround(r);
        if (ri > 256) ri = 256;
        rp.r[l] = (int)ri;
        lo.o[l] = acc;
        acc += 3 * (int)ri;        // three staged rows per level; total 4314 <= 4352
    }

    hipLaunchKernelGGL(style_kernel, dim3(192), dim3(256), 0, stream,
                       s, aw0, ab0, aw1, ab1, aw2, ab2, ws);
    hipLaunchKernelGGL(weff_kernel, dim3(BATCH), dim3(256), 0, stream,
                       w0, w1, w2, ws);
    hipLaunchKernelGGL(fused_kernel, dim3(NPIX / 512 * BATCH), dim3(512), 0, stream,
                       x, coords, ws, b0, b1, b2, out, rp, lo);
}